// Round 1
// baseline (5033.851 us; speedup 1.0000x reference)
//
#include <hip/hip_runtime.h>

#define B_    8
#define C_    256
#define HH    128
#define WW    128
#define HEADS_ 8
#define HD_   32
#define SCALE 0.17677669529663687f   // 32^-0.5

// ---- bf16 helpers (manual, RNE) ----
__device__ __forceinline__ unsigned short f2bf(float f) {
  unsigned int u = __float_as_uint(f);
  u = u + 0x7FFFu + ((u >> 16) & 1u);
  return (unsigned short)(u >> 16);
}
__device__ __forceinline__ float bf_lo(unsigned int u) { return __uint_as_float(u << 16); }
__device__ __forceinline__ float bf_hi(unsigned int u) { return __uint_as_float(u & 0xFFFF0000u); }

// LDS layout (bytes), total 160128 <= 163840:
//   [0          , 66560)  xst : ushort[128][260]   x row, transposed [s][c], bf16
//   [66560      , 66944)  bias: float[96]
//   [66944      , ...  )  UNION:
//       weights wl: ushort[96][256]                 (49152 B)   -- live during proj
//       qT/kT/vT : float[128][36] each (18432 B)    sc: ushort[128][132] (33792 B)
//       mp/sp    : float[512] each                  -- live during attention
#define OFF_BIAS 66560
#define OFF_UNI  66944
#define OFF_KT   (OFF_UNI + 18432)
#define OFF_VT   (OFF_UNI + 36864)
#define OFF_SC   (OFF_UNI + 55296)
#define OFF_MP   (OFF_UNI + 89088)
#define OFF_SP   (OFF_UNI + 91136)

template <int VERT>
__global__ __launch_bounds__(512, 1)
void pass_kernel(const float* __restrict__ x,
                 const float* __restrict__ Wq, const float* __restrict__ bq,
                 const float* __restrict__ Wk, const float* __restrict__ bk,
                 const float* __restrict__ Wv, const float* __restrict__ bv,
                 float* __restrict__ osum)
{
  __shared__ __align__(16) char smem[160128];
  unsigned short* xst  = (unsigned short*)(smem);
  float*          biasl= (float*)(smem + OFF_BIAS);
  unsigned short* wl   = (unsigned short*)(smem + OFF_UNI);
  float*          qT   = (float*)(smem + OFF_UNI);
  float*          kT   = (float*)(smem + OFF_KT);
  float*          vT   = (float*)(smem + OFF_VT);
  unsigned short* sc   = (unsigned short*)(smem + OFF_SC);
  float*          mp   = (float*)(smem + OFF_MP);
  float*          sp   = (float*)(smem + OFF_SP);

  const int tid = threadIdx.x;
  int b, r;
  if (VERT) {
    // XCD-aware swizzle: 16 consecutive w-columns pinned to one XCD for L2 reuse
    int xcd = blockIdx.x & 7, slot = blockIdx.x >> 3;
    r = xcd * 16 + (slot & 15);  b = slot >> 4;
  } else {
    b = blockIdx.x >> 7;  r = blockIdx.x & 127;
  }

  // ---- stage x row (bf16, transposed [s][c]) ----
  {
    const int s = tid & 127, cof = tid >> 7;
    for (int it = 0; it < 64; ++it) {
      int c  = it * 4 + cof;
      int gi = VERT ? (((b * C_ + c) * HH + s) * WW + r)
                    : (((b * C_ + c) * HH + r) * WW + s);
      xst[s * 260 + c] = f2bf(x[gi]);
    }
  }
  __syncthreads();

  const int w2 = tid & 63, dg = tid >> 6;     // projection mapping: 2 s-positions, 8 d-groups
  const int t  = tid & 127, quad = tid >> 7;  // attention mapping: query t, quarter

  for (int h = 0; h < HEADS_; ++h) {
    // ---- stage head weights (bf16) + biases ----
    for (int it = 0; it < 48; ++it) {
      int idx = it * 512 + tid;
      int c = idx & 255, dm = idx >> 8;       // dm = mat*32 + d, 0..95
      const float* Wm = dm < 32 ? Wq : (dm < 64 ? Wk : Wv);
      wl[dm * 256 + c] = f2bf(Wm[(h * HD_ + (dm & 31)) * C_ + c]);
    }
    if (tid < 96) {
      int mat = tid >> 5, d = tid & 31;
      const float* bm = mat == 0 ? bq : (mat == 1 ? bk : bv);
      biasl[tid] = bm[h * HD_ + d];
    }
    __syncthreads();

    // ---- projection: q,k,v[d][s] for this head, fp32 accumulate ----
    float acc[12][2];
    #pragma unroll
    for (int i = 0; i < 12; ++i) { acc[i][0] = 0.f; acc[i][1] = 0.f; }
    const int s0 = w2 * 2, s1 = s0 + 1;
    for (int cb = 0; cb < 64; ++cb) {
      const int c4 = cb * 4;
      uint2 xa = *(const uint2*)&xst[s0 * 260 + c4];
      uint2 xb = *(const uint2*)&xst[s1 * 260 + c4];
      float x0[4] = { bf_lo(xa.x), bf_hi(xa.x), bf_lo(xa.y), bf_hi(xa.y) };
      float x1[4] = { bf_lo(xb.x), bf_hi(xb.x), bf_lo(xb.y), bf_hi(xb.y) };
      #pragma unroll
      for (int mat = 0; mat < 3; ++mat) {
        #pragma unroll
        for (int di = 0; di < 4; ++di) {
          const int dm = mat * 32 + dg * 4 + di;
          uint2 wa = *(const uint2*)&wl[dm * 256 + c4];
          float w0 = bf_lo(wa.x), w1 = bf_hi(wa.x), w2v = bf_lo(wa.y), w3 = bf_hi(wa.y);
          float* a = acc[mat * 4 + di];
          a[0] += x0[0]*w0 + x0[1]*w1 + x0[2]*w2v + x0[3]*w3;
          a[1] += x1[0]*w0 + x1[1]*w1 + x1[2]*w2v + x1[3]*w3;
        }
      }
    }
    __syncthreads();   // everyone done reading wl (qT/kT/vT alias it)

    // ---- write q,k,v to LDS (+bias), layout [s][36] ----
    #pragma unroll
    for (int mat = 0; mat < 3; ++mat) {
      float* T = mat == 0 ? qT : (mat == 1 ? kT : vT);
      #pragma unroll
      for (int di = 0; di < 4; ++di) {
        int d = dg * 4 + di;
        float bia = biasl[mat * 32 + d];
        T[s0 * 36 + d] = acc[mat * 4 + di][0] + bia;
        T[s1 * 36 + d] = acc[mat * 4 + di][1] + bia;
      }
    }
    __syncthreads();

    // ---- phase 1: scores for query t, keys quad*32..+32; softmax ----
    float qreg[32];
    #pragma unroll
    for (int d = 0; d < 32; ++d) qreg[d] = qT[t * 36 + d];
    float sv[32];
    float lmax = -1e30f;
    #pragma unroll
    for (int j = 0; j < 32; ++j) {
      const float4* kp = (const float4*)&kT[(quad * 32 + j) * 36];
      float s = 0.f;
      #pragma unroll
      for (int d4 = 0; d4 < 8; ++d4) {
        float4 kv = kp[d4];
        s += qreg[d4*4]*kv.x + qreg[d4*4+1]*kv.y + qreg[d4*4+2]*kv.z + qreg[d4*4+3]*kv.w;
      }
      s *= SCALE; sv[j] = s; lmax = fmaxf(lmax, s);
    }
    mp[quad * 128 + t] = lmax;
    __syncthreads();
    const float m = fmaxf(fmaxf(mp[t], mp[128 + t]), fmaxf(mp[256 + t], mp[384 + t]));
    float lsum = 0.f;
    #pragma unroll
    for (int j = 0; j < 32; ++j) {
      float p = __expf(sv[j] - m);
      lsum += p;
      sc[t * 132 + quad * 32 + j] = f2bf(p);
    }
    sp[quad * 128 + t] = lsum;
    __syncthreads();
    const float stot = sp[t] + sp[128 + t] + sp[256 + t] + sp[384 + t];

    // ---- phase 2: out[d0..d0+8][t] = P @ V^T ----
    float o[8];
    #pragma unroll
    for (int j = 0; j < 8; ++j) o[j] = 0.f;
    const int d0 = quad * 8;
    for (int v4 = 0; v4 < 128; v4 += 4) {
      uint2 pu = *(const uint2*)&sc[t * 132 + v4];
      float p[4] = { bf_lo(pu.x), bf_hi(pu.x), bf_lo(pu.y), bf_hi(pu.y) };
      #pragma unroll
      for (int vv = 0; vv < 4; ++vv) {
        const float4* vp = (const float4*)&vT[(v4 + vv) * 36 + d0];
        float4 va = vp[0], vb = vp[1];
        o[0] += p[vv]*va.x; o[1] += p[vv]*va.y; o[2] += p[vv]*va.z; o[3] += p[vv]*va.w;
        o[4] += p[vv]*vb.x; o[5] += p[vv]*vb.y; o[6] += p[vv]*vb.z; o[7] += p[vv]*vb.w;
      }
    }
    const float rn = 1.f / stot;
    const int cbase = h * HD_ + d0;
    #pragma unroll
    for (int j = 0; j < 8; ++j) {
      float val = o[j] * rn;
      if (VERT) {
        int gi = ((b * C_ + cbase + j) * HH + t) * WW + r;
        osum[gi] += val;             // accumulate onto horizontal-pass result
      } else {
        int gi = ((b * C_ + cbase + j) * HH + r) * WW + t;
        osum[gi] = val;              // plain store: re-initializes d_out every call
      }
    }
    __syncthreads();   // protect union region before next head's weight staging
  }
}

// ---- final: out = Wo @ attnsum + bo + x ; reads d_out, stages row, overwrites ----
__global__ __launch_bounds__(256, 1)
void final_kernel(const float* __restrict__ x, const float* __restrict__ Wo,
                  const float* __restrict__ bo, float* __restrict__ out)
{
  __shared__ __align__(16) float asr[128 * 258];   // [w][c], pad 2
  const int tid = threadIdx.x;
  const int b = blockIdx.x >> 7, r = blockIdx.x & 127;
  {
    const int w = tid & 127, cof = tid >> 7;
    for (int it = 0; it < 128; ++it) {
      int c = it * 2 + cof;
      asr[w * 258 + c] = out[((b * C_ + c) * HH + r) * WW + w];
    }
  }
  __syncthreads();
  const int w = tid & 127, og = tid >> 7;
  const float2* av = (const float2*)&asr[w * 258];
  for (int ob = 0; ob < 32; ++ob) {
    const int o0 = og * 128 + ob * 4;
    float a0 = bo[o0], a1 = bo[o0 + 1], a2 = bo[o0 + 2], a3 = bo[o0 + 3];
    for (int c4 = 0; c4 < 64; ++c4) {
      float2 xlo = av[c4 * 2], xhi = av[c4 * 2 + 1];
      const float4 w0 = *(const float4*)&Wo[(o0    ) * C_ + c4 * 4];
      const float4 w1 = *(const float4*)&Wo[(o0 + 1) * C_ + c4 * 4];
      const float4 w2 = *(const float4*)&Wo[(o0 + 2) * C_ + c4 * 4];
      const float4 w3 = *(const float4*)&Wo[(o0 + 3) * C_ + c4 * 4];
      a0 += w0.x*xlo.x + w0.y*xlo.y + w0.z*xhi.x + w0.w*xhi.y;
      a1 += w1.x*xlo.x + w1.y*xlo.y + w1.z*xhi.x + w1.w*xhi.y;
      a2 += w2.x*xlo.x + w2.y*xlo.y + w2.z*xhi.x + w2.w*xhi.y;
      a3 += w3.x*xlo.x + w3.y*xlo.y + w3.z*xhi.x + w3.w*xhi.y;
    }
    const int base = ((b * C_ + o0) * HH + r) * WW + w;
    out[base           ] = a0 + x[base           ];
    out[base +   HH*WW ] = a1 + x[base +   HH*WW ];
    out[base + 2*HH*WW ] = a2 + x[base + 2*HH*WW ];
    out[base + 3*HH*WW ] = a3 + x[base + 3*HH*WW ];
  }
}

extern "C" void kernel_launch(void* const* d_in, const int* in_sizes, int n_in,
                              void* d_out, int out_size, void* d_ws, size_t ws_size,
                              hipStream_t stream) {
  const float* x  = (const float*)d_in[0];
  const float* Wq = (const float*)d_in[1];
  const float* bq = (const float*)d_in[2];
  const float* Wk = (const float*)d_in[3];
  const float* bk = (const float*)d_in[4];
  const float* Wv = (const float*)d_in[5];
  const float* bv = (const float*)d_in[6];
  const float* Wo = (const float*)d_in[7];
  const float* bo = (const float*)d_in[8];
  float* out = (float*)d_out;

  pass_kernel<0><<<dim3(B_ * HH), dim3(512), 0, stream>>>(x, Wq, bq, Wk, bk, Wv, bv, out);
  pass_kernel<1><<<dim3(B_ * WW), dim3(512), 0, stream>>>(x, Wq, bq, Wk, bk, Wv, bv, out);
  final_kernel  <<<dim3(B_ * HH), dim3(256), 0, stream>>>(x, Wo, bo, out);
}

// Round 2
// 1179.965 us; speedup vs baseline: 4.2661x; 4.2661x over previous
//
#include <hip/hip_runtime.h>

#define B_ 8
#define C_ 256
#define HH 128
#define WW 128
#define HEADS_ 8
#define SCALE 0.17677669529663687f   // 32^-0.5

typedef short v8s __attribute__((ext_vector_type(8)));
typedef float f32x4 __attribute__((ext_vector_type(4)));

__device__ __forceinline__ unsigned short f2bf(float f){
  unsigned int u = __float_as_uint(f);
  u += 0x7FFFu + ((u>>16)&1u);
  return (unsigned short)(u>>16);
}
__device__ __forceinline__ f32x4 mfma16(v8s a, v8s b, f32x4 c){
  return __builtin_amdgcn_mfma_f32_16x16x32_bf16(a,b,c,0,0,0);
}
// swizzled LDS index (ushort units): 16B chunks XORed with row low bits ->
// writes (lanes span rows) and b128 frag reads (16 lanes span rows) both <=2-way
__device__ __forceinline__ int xs_idx(int s,int c){ return s*256 + ((((c>>3)^(s&31))&31)<<3) + (c&7); }
__device__ __forceinline__ int wl_idx(int dm,int c){ return dm*256 + ((((c>>3)^(dm&31))&31)<<3) + (c&7); }

// LDS map (bytes):
//  [0,65536)        xs  : ushort[128][256] swz   -- x row (bf16), rows = s
//  [65536,65920)    biasl: float[96]
//  [65920,115072)   wl  : ushort[96][256] swz    -- per-head wT, OVERLAID after proj by:
//     [65920,76160)  ql : ushort[128][40]        (q * SCALE)
//     [76160,86400)  kl : ushort[128][40]
//     [86400,95104)  Vt : ushort[32][136]        (V transposed [d][s])
//  [115072,149888)  Pl  : ushort[128][136]       -- probabilities (normalized)
template<int VERT>
__global__ __launch_bounds__(512,1)
void pass_kernel(const float* __restrict__ x,
                 const float* __restrict__ Wq,const float* __restrict__ bq,
                 const float* __restrict__ Wk,const float* __restrict__ bk,
                 const float* __restrict__ Wv,const float* __restrict__ bv,
                 float* __restrict__ osum)
{
  __shared__ __align__(16) char smem[149888];
  unsigned short* xs = (unsigned short*)smem;
  float* biasl       = (float*)(smem + 65536);
  unsigned short* wl = (unsigned short*)(smem + 65920);
  unsigned short* ql = (unsigned short*)(smem + 65920);
  unsigned short* kl = (unsigned short*)(smem + 76160);
  unsigned short* Vt = (unsigned short*)(smem + 86400);
  unsigned short* Pl = (unsigned short*)(smem + 115072);

  const int tid = threadIdx.x;
  int b, r;
  if (VERT){ int xcd = blockIdx.x & 7, slot = blockIdx.x >> 3;
             r = xcd*16 + (slot & 15); b = slot >> 4; }      // 16 w-cols per XCD
  else     { b = blockIdx.x >> 7; r = blockIdx.x & 127; }

  // ---- stage x row -> xs (bf16, swizzled) ----
  {
    const int s = tid & 127, part = tid >> 7;
    #pragma unroll 4
    for (int it = 0; it < 32; ++it){
      int c = (it*4 + part)*2;
      int g0 = VERT ? ((b*C_ + c)*HH + s)*WW + r
                    : ((b*C_ + c)*HH + r)*WW + s;
      float f0 = x[g0], f1 = x[g0 + HH*WW];
      unsigned int pk = (unsigned int)f2bf(f0) | ((unsigned int)f2bf(f1)<<16);
      *(unsigned int*)(xs + xs_idx(s,c)) = pk;
    }
  }
  __syncthreads();

  const int lane = tid & 63, wv = tid >> 6;   // wave id == M-tile
  const int lr = lane & 15, lk = lane >> 4;
  const f32x4 zero4 = {0.f,0.f,0.f,0.f};

  for (int h = 0; h < HEADS_; ++h){
    // ---- stage per-head weights wT[dm][c] (bf16 swizzled) + biases ----
    for (int it = 0; it < 48; ++it){
      int idx = it*512 + tid;
      int dmx = idx >> 8, c = idx & 255;
      const float* Wm = dmx < 32 ? Wq : (dmx < 64 ? Wk : Wv);
      wl[wl_idx(dmx,c)] = f2bf(Wm[(h*32 + (dmx & 31))*C_ + c]);
    }
    if (tid < 96){
      int mat = tid >> 5;
      const float* bm = mat==0 ? bq : (mat==1 ? bk : bv);
      biasl[tid] = bm[h*32 + (tid & 31)];
    }
    __syncthreads();

    // ---- projection: [128 s] x [256 c] -> [96 dm], 48 MFMA/wave ----
    f32x4 acc[6];
    #pragma unroll
    for (int n = 0; n < 6; ++n) acc[n] = zero4;
    #pragma unroll
    for (int ks = 0; ks < 8; ++ks){
      int c0 = ks*32 + lk*8;
      v8s a = *(const v8s*)(xs + xs_idx(wv*16 + lr, c0));
      #pragma unroll
      for (int n = 0; n < 6; ++n){
        v8s bb = *(const v8s*)(wl + wl_idx(n*16 + lr, c0));
        acc[n] = mfma16(a, bb, acc[n]);
      }
    }
    __syncthreads();   // all waves done reading wl (q/k/Vt overlay it)

    // ---- scatter q,k,v (+bias) to LDS; scale folded into q ----
    #pragma unroll
    for (int n = 0; n < 6; ++n){
      float bia = biasl[n*16 + lr];
      #pragma unroll
      for (int rr = 0; rr < 4; ++rr){
        int so = wv*16 + lk*4 + rr;
        float val = acc[n][rr] + bia;
        if (n < 2)      ql[so*40 + n*16 + lr] = f2bf(val * SCALE);
        else if (n < 4) kl[so*40 + (n-2)*16 + lr] = f2bf(val);
        else            Vt[((n-4)*16 + lr)*136 + so] = f2bf(val);
      }
    }
    __syncthreads();

    // ---- QK^T: K=32 -> single MFMA k-step; 8 key tiles ----
    f32x4 sc[8];
    {
      v8s qa = *(const v8s*)(ql + (wv*16 + lr)*40 + lk*8);
      #pragma unroll
      for (int n = 0; n < 8; ++n){
        v8s kb = *(const v8s*)(kl + (n*16 + lr)*40 + lk*8);
        sc[n] = mfma16(qa, kb, zero4);
      }
    }
    // ---- softmax: row lives across 16 contiguous lanes -> shfl_xor reduce ----
    #pragma unroll
    for (int rr = 0; rr < 4; ++rr){
      float mx = sc[0][rr];
      #pragma unroll
      for (int n = 1; n < 8; ++n) mx = fmaxf(mx, sc[n][rr]);
      #pragma unroll
      for (int off = 1; off < 16; off <<= 1) mx = fmaxf(mx, __shfl_xor(mx, off, 16));
      float sm = 0.f;
      #pragma unroll
      for (int n = 0; n < 8; ++n){ float p = __expf(sc[n][rr] - mx); sc[n][rr] = p; sm += p; }
      #pragma unroll
      for (int off = 1; off < 16; off <<= 1) sm += __shfl_xor(sm, off, 16);
      float rcp = 1.f / sm;
      int so = wv*16 + lk*4 + rr;
      #pragma unroll
      for (int n = 0; n < 8; ++n) Pl[so*136 + n*16 + lr] = f2bf(sc[n][rr] * rcp);
    }
    __syncthreads();

    // ---- PV: M=128 s, N=32 d, K=128 keys ----
    f32x4 o0 = zero4, o1 = zero4;
    #pragma unroll
    for (int ks = 0; ks < 4; ++ks){
      v8s pa  = *(const v8s*)(Pl + (wv*16 + lr)*136 + ks*32 + lk*8);
      v8s vb0 = *(const v8s*)(Vt + (     lr)*136 + ks*32 + lk*8);
      v8s vb1 = *(const v8s*)(Vt + (16 + lr)*136 + ks*32 + lk*8);
      o0 = mfma16(pa, vb0, o0);
      o1 = mfma16(pa, vb1, o1);
    }
    // ---- write outputs: lane owns (s = wv*16+lk*4+rr, d = lr | 16+lr) ----
    if (!VERT){
      int base0 = ((b*C_ + h*32 + lr)*HH + r)*WW + wv*16 + lk*4;
      *(f32x4*)(osum + base0) = o0;                    // 4 consecutive w
      *(f32x4*)(osum + base0 + 16*HH*WW) = o1;
    } else {
      #pragma unroll
      for (int rr = 0; rr < 4; ++rr){
        int so = wv*16 + lk*4 + rr;
        int g0 = ((b*C_ + h*32 + lr)*HH + so)*WW + r;
        osum[g0] += o0[rr];
        osum[g0 + 16*HH*WW] += o1[rr];
      }
    }
    __syncthreads();  // protect overlay region before next head's restage
  }
}

// ---- final: out = Wo @ attnsum + bo + x (reads d_out, overwrites d_out) ----
__global__ __launch_bounds__(512,1)
void final_kernel(const float* __restrict__ x, const float* __restrict__ Wo,
                  const float* __restrict__ bo, float* __restrict__ out)
{
  __shared__ __align__(16) char smem[82048];
  unsigned short* asl = (unsigned short*)smem;            // [128 w][256 c] swz
  unsigned short* wol = (unsigned short*)(smem + 65536);  // [32 o][256 c] swz
  float* bol          = (float*)(smem + 81920);           // [32]

  const int tid = threadIdx.x;
  const int b = blockIdx.x >> 7, r = blockIdx.x & 127;
  {
    const int w = tid & 127, part = tid >> 7;
    #pragma unroll 4
    for (int it = 0; it < 32; ++it){
      int c = (it*4 + part)*2;
      int g0 = ((b*C_ + c)*HH + r)*WW + w;
      float f0 = out[g0], f1 = out[g0 + HH*WW];
      unsigned int pk = (unsigned int)f2bf(f0) | ((unsigned int)f2bf(f1)<<16);
      *(unsigned int*)(asl + xs_idx(w,c)) = pk;
    }
  }
  __syncthreads();

  const int lane = tid & 63, wv = tid >> 6;
  const int lr = lane & 15, lk = lane >> 4;
  const f32x4 zero4 = {0.f,0.f,0.f,0.f};

  for (int oc = 0; oc < 8; ++oc){
    for (int it = 0; it < 16; ++it){
      int idx = it*512 + tid;
      int o = idx >> 8, c = idx & 255;
      wol[wl_idx(o,c)] = f2bf(Wo[(oc*32 + o)*C_ + c]);
    }
    if (tid < 32) bol[tid] = bo[oc*32 + tid];
    __syncthreads();

    f32x4 a0 = zero4, a1 = zero4;
    #pragma unroll
    for (int ks = 0; ks < 8; ++ks){
      int c0 = ks*32 + lk*8;
      v8s av = *(const v8s*)(asl + xs_idx(wv*16 + lr, c0));
      v8s b0 = *(const v8s*)(wol + wl_idx(     lr, c0));
      v8s b1 = *(const v8s*)(wol + wl_idx(16 + lr, c0));
      a0 = mfma16(av, b0, a0);
      a1 = mfma16(av, b1, a1);
    }
    {
      int base0 = ((b*C_ + oc*32 + lr)*HH + r)*WW + wv*16 + lk*4;
      f32x4 xv0 = *(const f32x4*)(x + base0);
      f32x4 xv1 = *(const f32x4*)(x + base0 + 16*HH*WW);
      f32x4 r0 = a0 + xv0 + bol[lr];
      f32x4 r1 = a1 + xv1 + bol[16 + lr];
      *(f32x4*)(out + base0) = r0;
      *(f32x4*)(out + base0 + 16*HH*WW) = r1;
    }
    __syncthreads();
  }
}

extern "C" void kernel_launch(void* const* d_in, const int* in_sizes, int n_in,
                              void* d_out, int out_size, void* d_ws, size_t ws_size,
                              hipStream_t stream) {
  const float* x  = (const float*)d_in[0];
  const float* Wq = (const float*)d_in[1];
  const float* bq = (const float*)d_in[2];
  const float* Wk = (const float*)d_in[3];
  const float* bk = (const float*)d_in[4];
  const float* Wv = (const float*)d_in[5];
  const float* bv = (const float*)d_in[6];
  const float* Wo = (const float*)d_in[7];
  const float* bo = (const float*)d_in[8];
  float* out = (float*)d_out;

  pass_kernel<0><<<dim3(B_ * HH), dim3(512), 0, stream>>>(x, Wq, bq, Wk, bk, Wv, bv, out);
  pass_kernel<1><<<dim3(B_ * WW), dim3(512), 0, stream>>>(x, Wq, bq, Wk, bk, Wv, bv, out);
  final_kernel  <<<dim3(B_ * HH), dim3(512), 0, stream>>>(x, Wo, bo, out);
}

// Round 3
// 632.054 us; speedup vs baseline: 7.9643x; 1.8669x over previous
//
#include <hip/hip_runtime.h>

#define B_ 8
#define C_ 256
#define HH 128
#define WW 128
#define HEADS_ 8
#define SCALE 0.17677669529663687f   // 32^-0.5

typedef short v8s __attribute__((ext_vector_type(8)));
typedef float f32x4 __attribute__((ext_vector_type(4)));

__device__ __forceinline__ unsigned short f2bf(float f){
  unsigned int u = __float_as_uint(f);
  u += 0x7FFFu + ((u>>16)&1u);
  return (unsigned short)(u>>16);
}
__device__ __forceinline__ float bf_lo(unsigned int u) { return __uint_as_float(u << 16); }
__device__ __forceinline__ float bf_hi(unsigned int u) { return __uint_as_float(u & 0xFFFF0000u); }
__device__ __forceinline__ f32x4 mfma16(v8s a, v8s b, f32x4 c){
  return __builtin_amdgcn_mfma_f32_16x16x32_bf16(a,b,c,0,0,0);
}
__device__ __forceinline__ int xs_idx(int s,int c){ return s*256 + ((((c>>3)^(s&31))&31)<<3) + (c&7); }
__device__ __forceinline__ int wl_idx(int dm,int c){ return dm*256 + ((((c>>3)^(dm&31))&31)<<3) + (c&7); }
__device__ __forceinline__ void gload_lds16(const void* g, void* l){
  __builtin_amdgcn_global_load_lds((const __attribute__((address_space(1))) unsigned int*)g,
                                   (__attribute__((address_space(3))) unsigned int*)l, 16, 0, 0);
}

// ============================ FAST PATH ============================
// ws layout (bytes): [0, 393216) wsW: 8 heads x (96x256) bf16, pre-swizzled LDS image
//                    [393216, 524288) wsWo: 8 oc x (32x256) bf16 pre-swizzled
//                    [524288 ...) Qw, Kw, Vw: each [b][head][16384 pos][32 d] bf16 (67,108,864 B)
#define WS_NEED 201850880ULL

__global__ __launch_bounds__(512,4)
void prep_w_kernel(const float* __restrict__ Wq, const float* __restrict__ Wk,
                   const float* __restrict__ Wv, const float* __restrict__ Wo,
                   unsigned short* __restrict__ wsW, unsigned short* __restrict__ wsWo){
  const int bid = blockIdx.x, t = threadIdx.x;
  if (bid < 96){
    int h = bid/12, seg = bid%12;
    int dm = seg*8 + (t>>6), c = (t&63)*4;
    const float* Wm = dm<32 ? Wq : (dm<64 ? Wk : Wv);
    const float4 w4 = *(const float4*)&Wm[(h*32 + (dm&31))*C_ + c];
    ushort4 pk = { f2bf(w4.x), f2bf(w4.y), f2bf(w4.z), f2bf(w4.w) };
    *(ushort4*)(wsW + h*24576 + wl_idx(dm, c)) = pk;
  } else {
    int q = bid - 96;                  // 0..31
    int oc = q>>2, seg = q&3;
    int o = seg*8 + (t>>6), c = (t&63)*4;
    const float4 w4 = *(const float4*)&Wo[(oc*32+o)*C_ + c];
    ushort4 pk = { f2bf(w4.x), f2bf(w4.y), f2bf(w4.z), f2bf(w4.w) };
    *(ushort4*)(wsWo + oc*8192 + wl_idx(o, c)) = pk;
  }
}

// proj: per (b, 128-pos tile): stage x^T in LDS, loop heads: wl via global_load_lds,
// MFMA, repack to [pos][96] LDS, write q,k,v [pos][32d] coalesced.
__global__ __launch_bounds__(512,2)
void proj_kernel(const float* __restrict__ x,
                 const float* __restrict__ bq, const float* __restrict__ bk,
                 const float* __restrict__ bv,
                 const unsigned short* __restrict__ wsW,
                 unsigned short* __restrict__ Qw, unsigned short* __restrict__ Kw,
                 unsigned short* __restrict__ Vw){
  __shared__ __align__(16) char smem[141696];
  unsigned short* xs = (unsigned short*)smem;            // [128][256] swz (64K)
  unsigned short* wl = (unsigned short*)(smem + 65536);  // 96x256 (48K)
  unsigned short* rp = (unsigned short*)(smem + 114688); // [128][104] (26.6K)
  float* biasl       = (float*)(smem + 141312);          // [96]

  const int tid = threadIdx.x;
  const int b = blockIdx.x >> 7, pt = blockIdx.x & 127;
  const size_t pos0 = (size_t)pt * 128;

  {  // x -> xs: transpose+convert. thread: c pair (cq,cq+1), 4 consecutive pos
    const int cq = (tid>>5)*2, pl = (tid&31)*4;
    #pragma unroll
    for (int j=0;j<8;++j){
      int c0 = j*32 + cq;
      const float4 a0 = *(const float4*)&x[((size_t)(b*C_ + c0  ))*16384 + pos0 + pl];
      const float4 a1 = *(const float4*)&x[((size_t)(b*C_ + c0+1))*16384 + pos0 + pl];
      unsigned int p0 = (unsigned)f2bf(a0.x) | ((unsigned)f2bf(a1.x)<<16);
      unsigned int p1 = (unsigned)f2bf(a0.y) | ((unsigned)f2bf(a1.y)<<16);
      unsigned int p2 = (unsigned)f2bf(a0.z) | ((unsigned)f2bf(a1.z)<<16);
      unsigned int p3 = (unsigned)f2bf(a0.w) | ((unsigned)f2bf(a1.w)<<16);
      *(unsigned int*)&xs[xs_idx(pl+0, c0)] = p0;
      *(unsigned int*)&xs[xs_idx(pl+1, c0)] = p1;
      *(unsigned int*)&xs[xs_idx(pl+2, c0)] = p2;
      *(unsigned int*)&xs[xs_idx(pl+3, c0)] = p3;
    }
  }
  {  // issue wl(head 0)
    const char* wb = (const char*)wsW;
    for (int rIt=0;rIt<6;++rIt)
      gload_lds16(wb + (rIt*512+tid)*16, (char*)wl + (rIt*512+tid)*16);
  }

  const int lane = tid&63, wv = tid>>6, lr = lane&15, lk = lane>>4;
  const f32x4 zero4 = {0.f,0.f,0.f,0.f};

  for (int h=0; h<HEADS_; ++h){
    __syncthreads();                 // A: wl(h) ready (vmcnt drained), rp/biasl free
    if (tid<96){
      int mat = tid>>5;
      const float* bm = mat==0?bq:(mat==1?bk:bv);
      biasl[tid] = bm[h*32 + (tid&31)];
    }
    f32x4 acc[6];
    #pragma unroll
    for (int n=0;n<6;++n) acc[n]=zero4;
    #pragma unroll
    for (int ks=0;ks<8;++ks){
      int c0 = ks*32 + lk*8;
      v8s a = *(const v8s*)(xs + xs_idx(wv*16+lr, c0));
      #pragma unroll
      for (int n=0;n<6;++n){
        v8s bb = *(const v8s*)(wl + wl_idx(n*16+lr, c0));
        acc[n] = mfma16(a, bb, acc[n]);
      }
    }
    __syncthreads();                 // B: biasl visible; wl(h) free
    if (h < HEADS_-1){
      const char* wb = (const char*)wsW + (h+1)*49152;
      for (int rIt=0;rIt<6;++rIt)
        gload_lds16(wb + (rIt*512+tid)*16, (char*)wl + (rIt*512+tid)*16);
    }
    #pragma unroll
    for (int n=0;n<6;++n){
      int dm = n*16+lr;
      float bia = biasl[dm];
      #pragma unroll
      for (int rr=0;rr<4;++rr){
        int pos = wv*16 + lk*4 + rr;
        float val = acc[n][rr] + bia;
        if (n<2) val *= SCALE;       // fold softmax scale into q
        rp[pos*104 + dm] = f2bf(val);
      }
    }
    __syncthreads();                 // C: rp visible
    {
      int pos = tid>>2, ch = tid&3;
      v8s qd = *(const v8s*)&rp[pos*104 +      ch*8];
      v8s kd = *(const v8s*)&rp[pos*104 + 32 + ch*8];
      v8s vd = *(const v8s*)&rp[pos*104 + 64 + ch*8];
      size_t ob = ((size_t)(b*HEADS_+h)*16384 + pos0 + pos)*32 + ch*8;
      *(v8s*)(Qw + ob) = qd;
      *(v8s*)(Kw + ob) = kd;
      *(v8s*)(Vw + ob) = vd;
    }
  }
}

// attn: block = (b, head, row-or-col). 512 thr, 8 waves, one q-tile/wave.
// LDS 53.8KB -> 2 blocks/CU. One barrier.
template<int VERT>
__global__ __launch_bounds__(512,4)
void attn_kernel(const unsigned short* __restrict__ Qw, const unsigned short* __restrict__ Kw,
                 const unsigned short* __restrict__ Vw, float* __restrict__ osum){
  __shared__ __align__(16) char smem[53760];
  unsigned short* kl = (unsigned short*)smem;             // [128][40]
  unsigned short* Vt = (unsigned short*)(smem + 10240);   // [32][136]
  unsigned short* Pl = (unsigned short*)(smem + 18944);   // [128][136]

  const int tid = threadIdx.x;
  int b, head, fix;
  if (VERT){ int xcd = blockIdx.x&7, rest = blockIdx.x>>3;
             fix = xcd*16 + (rest&15); head = (rest>>4)&7; b = rest>>7; }
  else     { head = blockIdx.x&7; fix = (blockIdx.x>>3)&127; b = blockIdx.x>>10; }
  const size_t tb = (size_t)(b*HEADS_+head)*16384*32;
  const int lane = tid&63, wv = tid>>6, lr = lane&15, lk = lane>>4;

  {  // stage K, V (V transposed to [d][pos])
    int pl = tid>>2, ch = tid&3;
    size_t g = tb + ( VERT ? ((size_t)pl*128 + fix) : ((size_t)fix*128 + pl) )*32 + ch*8;
    v8s kv = *(const v8s*)(Kw + g);
    v8s vv = *(const v8s*)(Vw + g);
    *(v8s*)&kl[pl*40 + ch*8] = kv;
    #pragma unroll
    for (int j=0;j<8;++j) Vt[(ch*8+j)*136 + pl] = (unsigned short)vv[j];
  }
  const int posq = VERT ? (wv*16+lr)*128 + fix : fix*128 + wv*16+lr;
  v8s qa = *(const v8s*)(Qw + tb + (size_t)posq*32 + lk*8);
  __syncthreads();

  const f32x4 zero4 = {0.f,0.f,0.f,0.f};
  f32x4 sc[8];
  #pragma unroll
  for (int kt=0;kt<8;++kt){
    v8s kb = *(const v8s*)&kl[(kt*16+lr)*40 + lk*8];
    sc[kt] = mfma16(qa, kb, zero4);
  }
  float rn[4];
  #pragma unroll
  for (int rr=0;rr<4;++rr){
    float mx = sc[0][rr];
    #pragma unroll
    for (int kt=1;kt<8;++kt) mx = fmaxf(mx, sc[kt][rr]);
    #pragma unroll
    for (int off=1;off<16;off<<=1) mx = fmaxf(mx, __shfl_xor(mx, off, 16));
    float sm = 0.f;
    const int prow = (wv*16 + lk*4 + rr)*136;
    #pragma unroll
    for (int kt=0;kt<8;++kt){
      float p = __expf(sc[kt][rr]-mx);
      sm += p;
      Pl[prow + kt*16 + lr] = f2bf(p);      // unnormalized; 1/sum folded into epilogue
    }
    #pragma unroll
    for (int off=1;off<16;off<<=1) sm += __shfl_xor(sm, off, 16);
    rn[rr] = 1.f/sm;
  }
  // PV (Pl rows are wave-private -> no barrier needed; lgkmcnt ordering suffices)
  f32x4 o0 = zero4, o1 = zero4;
  #pragma unroll
  for (int ks=0;ks<4;++ks){
    v8s pa = *(const v8s*)&Pl[(wv*16+lr)*136 + ks*32 + lk*8];
    v8s v0 = *(const v8s*)&Vt[(     lr)*136 + ks*32 + lk*8];
    v8s v1 = *(const v8s*)&Vt[(16 + lr)*136 + ks*32 + lk*8];
    o0 = mfma16(pa, v0, o0);
    o1 = mfma16(pa, v1, o1);
  }
  f32x4 rnv = {rn[0],rn[1],rn[2],rn[3]};
  o0 *= rnv; o1 *= rnv;
  if (!VERT){
    size_t base = ((size_t)(b*C_ + head*32 + lr)*HH + fix)*WW + wv*16 + lk*4;
    *(f32x4*)(osum + base) = o0;
    *(f32x4*)(osum + base + (size_t)16*HH*WW) = o1;
  } else {
    #pragma unroll
    for (int rr=0;rr<4;++rr){
      size_t g = ((size_t)(b*C_ + head*32 + lr)*HH + wv*16+lk*4+rr)*WW + fix;
      osum[g] += o0[rr];
      osum[g + (size_t)16*HH*WW] += o1[rr];
    }
  }
}

__global__ __launch_bounds__(512,1)
void final_fast_kernel(const float* __restrict__ x, const unsigned short* __restrict__ wsWo,
                       const float* __restrict__ bo, float* __restrict__ out)
{
  __shared__ __align__(16) char smem[82048];
  unsigned short* asl = (unsigned short*)smem;            // [128 w][256 c] swz
  unsigned short* wol = (unsigned short*)(smem + 65536);  // [32 o][256 c] swz
  float* bol          = (float*)(smem + 81920);           // [32]

  const int tid = threadIdx.x;
  const int b = blockIdx.x >> 7, r = blockIdx.x & 127;
  {
    const int w = tid & 127, part = tid >> 7;
    #pragma unroll 4
    for (int it = 0; it < 32; ++it){
      int c = (it*4 + part)*2;
      int g0 = ((b*C_ + c)*HH + r)*WW + w;
      float f0 = out[g0], f1 = out[g0 + HH*WW];
      unsigned int pk = (unsigned int)f2bf(f0) | ((unsigned int)f2bf(f1)<<16);
      *(unsigned int*)(asl + xs_idx(w,c)) = pk;
    }
  }
  const int lane = tid & 63, wv = tid >> 6;
  const int lr = lane & 15, lk = lane >> 4;
  const f32x4 zero4 = {0.f,0.f,0.f,0.f};

  for (int oc = 0; oc < 8; ++oc){
    {
      const char* wb = (const char*)wsWo + oc*16384;
      for (int rIt=0;rIt<2;++rIt)
        gload_lds16(wb + (rIt*512+tid)*16, (char*)wol + (rIt*512+tid)*16);
    }
    if (tid < 32) bol[tid] = bo[oc*32 + tid];
    __syncthreads();

    f32x4 a0 = zero4, a1 = zero4;
    #pragma unroll
    for (int ks = 0; ks < 8; ++ks){
      int c0 = ks*32 + lk*8;
      v8s av = *(const v8s*)(asl + xs_idx(wv*16 + lr, c0));
      v8s b0 = *(const v8s*)(wol + wl_idx(     lr, c0));
      v8s b1 = *(const v8s*)(wol + wl_idx(16 + lr, c0));
      a0 = mfma16(av, b0, a0);
      a1 = mfma16(av, b1, a1);
    }
    {
      int base0 = ((b*C_ + oc*32 + lr)*HH + r)*WW + wv*16 + lk*4;
      f32x4 xv0 = *(const f32x4*)(x + base0);
      f32x4 xv1 = *(const f32x4*)(x + base0 + 16*HH*WW);
      f32x4 r0 = a0 + xv0 + bol[lr];
      f32x4 r1 = a1 + xv1 + bol[16 + lr];
      *(f32x4*)(out + base0) = r0;
      *(f32x4*)(out + base0 + 16*HH*WW) = r1;
    }
    __syncthreads();
  }
}

// ============================ FALLBACK (R2, known-good) ============================
template<int VERT>
__global__ __launch_bounds__(512,1)
void pass_kernel(const float* __restrict__ x,
                 const float* __restrict__ Wq,const float* __restrict__ bq,
                 const float* __restrict__ Wk,const float* __restrict__ bk,
                 const float* __restrict__ Wv,const float* __restrict__ bv,
                 float* __restrict__ osum)
{
  __shared__ __align__(16) char smem[149888];
  unsigned short* xs = (unsigned short*)smem;
  float* biasl       = (float*)(smem + 65536);
  unsigned short* wl = (unsigned short*)(smem + 65920);
  unsigned short* ql = (unsigned short*)(smem + 65920);
  unsigned short* kl = (unsigned short*)(smem + 76160);
  unsigned short* Vt = (unsigned short*)(smem + 86400);
  unsigned short* Pl = (unsigned short*)(smem + 115072);

  const int tid = threadIdx.x;
  int b, r;
  if (VERT){ int xcd = blockIdx.x & 7, slot = blockIdx.x >> 3;
             r = xcd*16 + (slot & 15); b = slot >> 4; }
  else     { b = blockIdx.x >> 7; r = blockIdx.x & 127; }

  {
    const int s = tid & 127, part = tid >> 7;
    #pragma unroll 4
    for (int it = 0; it < 32; ++it){
      int c = (it*4 + part)*2;
      int g0 = VERT ? ((b*C_ + c)*HH + s)*WW + r
                    : ((b*C_ + c)*HH + r)*WW + s;
      float f0 = x[g0], f1 = x[g0 + HH*WW];
      unsigned int pk = (unsigned int)f2bf(f0) | ((unsigned int)f2bf(f1)<<16);
      *(unsigned int*)(xs + xs_idx(s,c)) = pk;
    }
  }
  __syncthreads();

  const int lane = tid & 63, wv = tid >> 6;
  const int lr = lane & 15, lk = lane >> 4;
  const f32x4 zero4 = {0.f,0.f,0.f,0.f};

  for (int h = 0; h < HEADS_; ++h){
    for (int it = 0; it < 48; ++it){
      int idx = it*512 + tid;
      int dmx = idx >> 8, c = idx & 255;
      const float* Wm = dmx < 32 ? Wq : (dmx < 64 ? Wk : Wv);
      wl[wl_idx(dmx,c)] = f2bf(Wm[(h*32 + (dmx & 31))*C_ + c]);
    }
    if (tid < 96){
      int mat = tid >> 5;
      const float* bm = mat==0 ? bq : (mat==1 ? bk : bv);
      biasl[tid] = bm[h*32 + (tid & 31)];
    }
    __syncthreads();

    f32x4 acc[6];
    #pragma unroll
    for (int n = 0; n < 6; ++n) acc[n] = zero4;
    #pragma unroll
    for (int ks = 0; ks < 8; ++ks){
      int c0 = ks*32 + lk*8;
      v8s a = *(const v8s*)(xs + xs_idx(wv*16 + lr, c0));
      #pragma unroll
      for (int n = 0; n < 6; ++n){
        v8s bb = *(const v8s*)(wl + wl_idx(n*16 + lr, c0));
        acc[n] = mfma16(a, bb, acc[n]);
      }
    }
    __syncthreads();

    #pragma unroll
    for (int n = 0; n < 6; ++n){
      float bia = biasl[n*16 + lr];
      #pragma unroll
      for (int rr = 0; rr < 4; ++rr){
        int so = wv*16 + lk*4 + rr;
        float val = acc[n][rr] + bia;
        if (n < 2)      ql[so*40 + n*16 + lr] = f2bf(val * SCALE);
        else if (n < 4) kl[so*40 + (n-2)*16 + lr] = f2bf(val);
        else            Vt[((n-4)*16 + lr)*136 + so] = f2bf(val);
      }
    }
    __syncthreads();

    f32x4 sc[8];
    {
      v8s qa = *(const v8s*)(ql + (wv*16 + lr)*40 + lk*8);
      #pragma unroll
      for (int n = 0; n < 8; ++n){
        v8s kb = *(const v8s*)(kl + (n*16 + lr)*40 + lk*8);
        sc[n] = mfma16(qa, kb, zero4);
      }
    }
    #pragma unroll
    for (int rr = 0; rr < 4; ++rr){
      float mx = sc[0][rr];
      #pragma unroll
      for (int n = 1; n < 8; ++n) mx = fmaxf(mx, sc[n][rr]);
      #pragma unroll
      for (int off = 1; off < 16; off <<= 1) mx = fmaxf(mx, __shfl_xor(mx, off, 16));
      float sm = 0.f;
      #pragma unroll
      for (int n = 0; n < 8; ++n){ float p = __expf(sc[n][rr] - mx); sc[n][rr] = p; sm += p; }
      #pragma unroll
      for (int off = 1; off < 16; off <<= 1) sm += __shfl_xor(sm, off, 16);
      float rcp = 1.f / sm;
      int so = wv*16 + lk*4 + rr;
      #pragma unroll
      for (int n = 0; n < 8; ++n) Pl[so*136 + n*16 + lr] = f2bf(sc[n][rr] * rcp);
    }
    __syncthreads();

    f32x4 o0 = zero4, o1 = zero4;
    #pragma unroll
    for (int ks = 0; ks < 4; ++ks){
      v8s pa  = *(const v8s*)(Pl + (wv*16 + lr)*136 + ks*32 + lk*8);
      v8s vb0 = *(const v8s*)(Vt + (     lr)*136 + ks*32 + lk*8);
      v8s vb1 = *(const v8s*)(Vt + (16 + lr)*136 + ks*32 + lk*8);
      o0 = mfma16(pa, vb0, o0);
      o1 = mfma16(pa, vb1, o1);
    }
    if (!VERT){
      int base0 = ((b*C_ + h*32 + lr)*HH + r)*WW + wv*16 + lk*4;
      *(f32x4*)(osum + base0) = o0;
      *(f32x4*)(osum + base0 + 16*HH*WW) = o1;
    } else {
      #pragma unroll
      for (int rr = 0; rr < 4; ++rr){
        int so = wv*16 + lk*4 + rr;
        int g0 = ((b*C_ + h*32 + lr)*HH + so)*WW + r;
        osum[g0] += o0[rr];
        osum[g0 + 16*HH*WW] += o1[rr];
      }
    }
    __syncthreads();
  }
}

__global__ __launch_bounds__(512,1)
void final_kernel(const float* __restrict__ x, const float* __restrict__ Wo,
                  const float* __restrict__ bo, float* __restrict__ out)
{
  __shared__ __align__(16) char smem[82048];
  unsigned short* asl = (unsigned short*)smem;
  unsigned short* wol = (unsigned short*)(smem + 65536);
  float* bol          = (float*)(smem + 81920);

  const int tid = threadIdx.x;
  const int b = blockIdx.x >> 7, r = blockIdx.x & 127;
  {
    const int w = tid & 127, part = tid >> 7;
    #pragma unroll 4
    for (int it = 0; it < 32; ++it){
      int c = (it*4 + part)*2;
      int g0 = ((b*C_ + c)*HH + r)*WW + w;
      float f0 = out[g0], f1 = out[g0 + HH*WW];
      unsigned int pk = (unsigned int)f2bf(f0) | ((unsigned int)f2bf(f1)<<16);
      *(unsigned int*)(asl + xs_idx(w,c)) = pk;
    }
  }
  const int lane = tid & 63, wv = tid >> 6;
  const int lr = lane & 15, lk = lane >> 4;
  const f32x4 zero4 = {0.f,0.f,0.f,0.f};

  for (int oc = 0; oc < 8; ++oc){
    for (int it = 0; it < 16; ++it){
      int idx = it*512 + tid;
      int o = idx >> 8, c = idx & 255;
      wol[wl_idx(o,c)] = f2bf(Wo[(oc*32 + o)*C_ + c]);
    }
    if (tid < 32) bol[tid] = bo[oc*32 + tid];
    __syncthreads();

    f32x4 a0 = zero4, a1 = zero4;
    #pragma unroll
    for (int ks = 0; ks < 8; ++ks){
      int c0 = ks*32 + lk*8;
      v8s av = *(const v8s*)(asl + xs_idx(wv*16 + lr, c0));
      v8s b0 = *(const v8s*)(wol + wl_idx(     lr, c0));
      v8s b1 = *(const v8s*)(wol + wl_idx(16 + lr, c0));
      a0 = mfma16(av, b0, a0);
      a1 = mfma16(av, b1, a1);
    }
    {
      int base0 = ((b*C_ + oc*32 + lr)*HH + r)*WW + wv*16 + lk*4;
      f32x4 xv0 = *(const f32x4*)(x + base0);
      f32x4 xv1 = *(const f32x4*)(x + base0 + 16*HH*WW);
      f32x4 r0 = a0 + xv0 + bol[lr];
      f32x4 r1 = a1 + xv1 + bol[16 + lr];
      *(f32x4*)(out + base0) = r0;
      *(f32x4*)(out + base0 + 16*HH*WW) = r1;
    }
    __syncthreads();
  }
}

extern "C" void kernel_launch(void* const* d_in, const int* in_sizes, int n_in,
                              void* d_out, int out_size, void* d_ws, size_t ws_size,
                              hipStream_t stream) {
  const float* x  = (const float*)d_in[0];
  const float* Wq = (const float*)d_in[1];
  const float* bq = (const float*)d_in[2];
  const float* Wk = (const float*)d_in[3];
  const float* bk = (const float*)d_in[4];
  const float* Wv = (const float*)d_in[5];
  const float* bv = (const float*)d_in[6];
  const float* Wo = (const float*)d_in[7];
  const float* bo = (const float*)d_in[8];
  float* out = (float*)d_out;

  if (ws_size >= WS_NEED) {
    unsigned short* wsW  = (unsigned short*)d_ws;
    unsigned short* wsWo = (unsigned short*)((char*)d_ws + 393216);
    unsigned short* Qw   = (unsigned short*)((char*)d_ws + 524288);
    unsigned short* Kw   = Qw + 33554432;
    unsigned short* Vw   = Kw + 33554432;
    prep_w_kernel<<<dim3(128),  dim3(512), 0, stream>>>(Wq, Wk, Wv, Wo, wsW, wsWo);
    proj_kernel  <<<dim3(1024), dim3(512), 0, stream>>>(x, bq, bk, bv, wsW, Qw, Kw, Vw);
    attn_kernel<0><<<dim3(8192), dim3(512), 0, stream>>>(Qw, Kw, Vw, out);
    attn_kernel<1><<<dim3(8192), dim3(512), 0, stream>>>(Qw, Kw, Vw, out);
    final_fast_kernel<<<dim3(1024), dim3(512), 0, stream>>>(x, wsWo, bo, out);
  } else {
    pass_kernel<0><<<dim3(B_ * HH), dim3(512), 0, stream>>>(x, Wq, bq, Wk, bk, Wv, bv, out);
    pass_kernel<1><<<dim3(B_ * WW), dim3(512), 0, stream>>>(x, Wq, bq, Wk, bk, Wv, bv, out);
    final_kernel  <<<dim3(B_ * HH), dim3(512), 0, stream>>>(x, Wo, bo, out);
  }
}

// Round 4
// 313.583 us; speedup vs baseline: 16.0527x; 2.0156x over previous
//
#include <hip/hip_runtime.h>

#define B_ 8
#define C_ 256
#define HH 128
#define WW 128
#define HEADS_ 8
#define SCALE 0.17677669529663687f   // 32^-0.5

typedef short v8s __attribute__((ext_vector_type(8)));
typedef float f32x4 __attribute__((ext_vector_type(4)));

__device__ __forceinline__ unsigned short f2bf(float f){
  unsigned int u = __float_as_uint(f);
  u += 0x7FFFu + ((u>>16)&1u);
  return (unsigned short)(u>>16);
}
__device__ __forceinline__ float bf2f(unsigned short s){ return __uint_as_float(((unsigned int)s)<<16); }
__device__ __forceinline__ f32x4 mfma16(v8s a, v8s b, f32x4 c){
  return __builtin_amdgcn_mfma_f32_16x16x32_bf16(a,b,c,0,0,0);
}
__device__ __forceinline__ int xs_idx(int s,int c){ return s*256 + ((((c>>3)^(s&31))&31)<<3) + (c&7); }
__device__ __forceinline__ int wl_idx(int dm,int c){ return dm*256 + ((((c>>3)^(dm&31))&31)<<3) + (c&7); }
__device__ __forceinline__ void gload_lds16(const void* g, void* l){
  __builtin_amdgcn_global_load_lds((const __attribute__((address_space(1))) unsigned int*)g,
                                   (__attribute__((address_space(3))) unsigned int*)l, 16, 0, 0);
}

// ws layout (bytes):
//   [0, 393216)            wsW : 8 heads x (96x256) bf16 pre-swizzled
//   [393216, 524288)       wsWo: 8 oc x (32x256) bf16 pre-swizzled
//   [524288, +3*67108864)  Qw, Kw, Vw : [b][head][16384 pos][32 d] bf16
//   [201850880, +67108864) Ah  : [b][16384 pos][256 c] bf16, chunk-swizzled (^pos&31)
#define WS_NEED1 201850880ULL
#define WS_NEED2 268959744ULL

__global__ __launch_bounds__(512,4)
void prep_w_kernel(const float* __restrict__ Wq, const float* __restrict__ Wk,
                   const float* __restrict__ Wv, const float* __restrict__ Wo,
                   unsigned short* __restrict__ wsW, unsigned short* __restrict__ wsWo){
  const int bid = blockIdx.x, t = threadIdx.x;
  if (bid < 96){
    int h = bid/12, seg = bid%12;
    int dm = seg*8 + (t>>6), c = (t&63)*4;
    const float* Wm = dm<32 ? Wq : (dm<64 ? Wk : Wv);
    const float4 w4 = *(const float4*)&Wm[(h*32 + (dm&31))*C_ + c];
    ushort4 pk = { f2bf(w4.x), f2bf(w4.y), f2bf(w4.z), f2bf(w4.w) };
    *(ushort4*)(wsW + h*24576 + wl_idx(dm, c)) = pk;
  } else {
    int q = bid - 96;
    int oc = q>>2, seg = q&3;
    int o = seg*8 + (t>>6), c = (t&63)*4;
    const float4 w4 = *(const float4*)&Wo[(oc*32+o)*C_ + c];
    ushort4 pk = { f2bf(w4.x), f2bf(w4.y), f2bf(w4.z), f2bf(w4.w) };
    *(ushort4*)(wsWo + oc*8192 + wl_idx(o, c)) = pk;
  }
}

__global__ __launch_bounds__(512,2)
void proj_kernel(const float* __restrict__ x,
                 const float* __restrict__ bq, const float* __restrict__ bk,
                 const float* __restrict__ bv,
                 const unsigned short* __restrict__ wsW,
                 unsigned short* __restrict__ Qw, unsigned short* __restrict__ Kw,
                 unsigned short* __restrict__ Vw){
  __shared__ __align__(16) char smem[141696];
  unsigned short* xs = (unsigned short*)smem;            // [128][256] swz
  unsigned short* wl = (unsigned short*)(smem + 65536);  // 96x256
  unsigned short* rp = (unsigned short*)(smem + 114688); // [128][104]
  float* biasl       = (float*)(smem + 141312);          // [96]

  const int tid = threadIdx.x;
  const int b = blockIdx.x >> 7, pt = blockIdx.x & 127;
  const size_t pos0 = (size_t)pt * 128;

  {
    const int cq = (tid>>5)*2, pl = (tid&31)*4;
    #pragma unroll
    for (int j=0;j<8;++j){
      int c0 = j*32 + cq;
      const float4 a0 = *(const float4*)&x[((size_t)(b*C_ + c0  ))*16384 + pos0 + pl];
      const float4 a1 = *(const float4*)&x[((size_t)(b*C_ + c0+1))*16384 + pos0 + pl];
      unsigned int p0 = (unsigned)f2bf(a0.x) | ((unsigned)f2bf(a1.x)<<16);
      unsigned int p1 = (unsigned)f2bf(a0.y) | ((unsigned)f2bf(a1.y)<<16);
      unsigned int p2 = (unsigned)f2bf(a0.z) | ((unsigned)f2bf(a1.z)<<16);
      unsigned int p3 = (unsigned)f2bf(a0.w) | ((unsigned)f2bf(a1.w)<<16);
      *(unsigned int*)&xs[xs_idx(pl+0, c0)] = p0;
      *(unsigned int*)&xs[xs_idx(pl+1, c0)] = p1;
      *(unsigned int*)&xs[xs_idx(pl+2, c0)] = p2;
      *(unsigned int*)&xs[xs_idx(pl+3, c0)] = p3;
    }
  }
  {
    const char* wb = (const char*)wsW;
    for (int rIt=0;rIt<6;++rIt)
      gload_lds16(wb + (rIt*512+tid)*16, (char*)wl + (rIt*512+tid)*16);
  }

  const int lane = tid&63, wv = tid>>6, lr = lane&15, lk = lane>>4;
  const f32x4 zero4 = {0.f,0.f,0.f,0.f};

  for (int h=0; h<HEADS_; ++h){
    __syncthreads();
    if (tid<96){
      int mat = tid>>5;
      const float* bm = mat==0?bq:(mat==1?bk:bv);
      biasl[tid] = bm[h*32 + (tid&31)];
    }
    f32x4 acc[6];
    #pragma unroll
    for (int n=0;n<6;++n) acc[n]=zero4;
    #pragma unroll
    for (int ks=0;ks<8;++ks){
      int c0 = ks*32 + lk*8;
      v8s a = *(const v8s*)(xs + xs_idx(wv*16+lr, c0));
      #pragma unroll
      for (int n=0;n<6;++n){
        v8s bb = *(const v8s*)(wl + wl_idx(n*16+lr, c0));
        acc[n] = mfma16(a, bb, acc[n]);
      }
    }
    __syncthreads();
    if (h < HEADS_-1){
      const char* wb = (const char*)wsW + (h+1)*49152;
      for (int rIt=0;rIt<6;++rIt)
        gload_lds16(wb + (rIt*512+tid)*16, (char*)wl + (rIt*512+tid)*16);
    }
    #pragma unroll
    for (int n=0;n<6;++n){
      int dm = n*16+lr;
      float bia = biasl[dm];
      #pragma unroll
      for (int rr=0;rr<4;++rr){
        int pos = wv*16 + lk*4 + rr;
        float val = acc[n][rr] + bia;
        if (n<2) val *= SCALE;
        rp[pos*104 + dm] = f2bf(val);
      }
    }
    __syncthreads();
    {
      int pos = tid>>2, ch = tid&3;
      v8s qd = *(const v8s*)&rp[pos*104 +      ch*8];
      v8s kd = *(const v8s*)&rp[pos*104 + 32 + ch*8];
      v8s vd = *(const v8s*)&rp[pos*104 + 64 + ch*8];
      size_t ob = ((size_t)(b*HEADS_+h)*16384 + pos0 + pos)*32 + ch*8;
      *(v8s*)(Qw + ob) = qd;
      *(v8s*)(Kw + ob) = kd;
      *(v8s*)(Vw + ob) = vd;
    }
  }
}

// ---- attn2: swapped QK^T (P lane-local), in-register PV, bf16 Ah output ----
// Key math (from verified m89 C-layout): D=mfma(A=K,B=Q) gives lane(lr,lk) reg rr
//   = P[key = kt*16 + lk*4 + rr][query = wv*16 + lr].
// PV contraction uses permuted key order kappa = ks*32 + (j>>2)*16 + lk*4 + (j&3),
// so A-frag(step ks) = lane's own pk[4ks..4ks+3]; V staged at slot(key) to match.
template<int VERT>
__global__ __launch_bounds__(512,6)
void attn2_kernel(const unsigned short* __restrict__ Qw, const unsigned short* __restrict__ Kw,
                  const unsigned short* __restrict__ Vw, unsigned short* __restrict__ Ah){
  __shared__ __align__(16) char smem[37376];
  unsigned short* kl = (unsigned short*)smem;            // [128 key][40 d]
  unsigned short* Vt = (unsigned short*)(smem + 10240);  // [32 d][136 slot]
  float*          ob = (float*)(smem + 18944);           // [128 s][36 d]

  const int tid = threadIdx.x;
  int b, head, fix;
  if (VERT){ int xcd = blockIdx.x&7, rest = blockIdx.x>>3;
             fix = xcd*16 + (rest&15); head = (rest>>4)&7; b = rest>>7; }
  else     { head = blockIdx.x&7; fix = (blockIdx.x>>3)&127; b = blockIdx.x>>10; }
  const size_t tb = (size_t)(b*HEADS_+head)*16384*32;
  const int lane = tid&63, wvq = tid>>6, lr = lane&15, lk = lane>>4;
  const f32x4 zero4 = {0.f,0.f,0.f,0.f};

  {  // stage K [key][d], V [d][slot(key)]
    int pl = tid>>2, ch = tid&3;
    size_t g = tb + (VERT ? ((size_t)pl*128 + fix) : ((size_t)fix*128 + pl))*32 + ch*8;
    v8s kv = *(const v8s*)(Kw + g);
    v8s vv = *(const v8s*)(Vw + g);
    *(v8s*)&kl[pl*40 + ch*8] = kv;
    int slot = (pl & ~31) | (((pl>>2)&3)<<3) | (((pl>>4)&1)<<2) | (pl&3);
    #pragma unroll
    for (int j=0;j<8;++j) Vt[(ch*8+j)*136 + slot] = (unsigned short)vv[j];
  }
  const int posq = VERT ? (wvq*16+lr)*128 + fix : fix*128 + (wvq*16+lr);
  v8s qa = *(const v8s*)(Qw + tb + (size_t)posq*32 + lk*8);
  __syncthreads();

  // QK^T swapped: lane owns 32 scores (keys = kt*16 + lk*4 + rr) of query wvq*16+lr
  f32x4 sc[8];
  #pragma unroll
  for (int kt=0;kt<8;++kt){
    v8s kb = *(const v8s*)&kl[(kt*16+lr)*40 + lk*8];
    sc[kt] = mfma16(kb, qa, zero4);
  }
  // softmax: 31 in-lane fmax + 2 shfl (lanes lr, lr+16, lr+32, lr+48 share query)
  float mx = sc[0][0];
  #pragma unroll
  for (int kt=0;kt<8;++kt){
    #pragma unroll
    for (int rr=0;rr<4;++rr) mx = fmaxf(mx, sc[kt][rr]);
  }
  mx = fmaxf(mx, __shfl_xor(mx, 16));
  mx = fmaxf(mx, __shfl_xor(mx, 32));
  float sm = 0.f;
  #pragma unroll
  for (int kt=0;kt<8;++kt){
    #pragma unroll
    for (int rr=0;rr<4;++rr){ float p = __expf(sc[kt][rr]-mx); sc[kt][rr]=p; sm += p; }
  }
  sm += __shfl_xor(sm, 16);
  sm += __shfl_xor(sm, 32);
  const float rn = 1.f/sm;
  // normalize + pack: pk[kt*2+h] = bf16pair(sc[kt][2h], sc[kt][2h+1])
  unsigned int pk[16];
  #pragma unroll
  for (int kt=0;kt<8;++kt){
    pk[kt*2  ] = (unsigned)f2bf(sc[kt][0]*rn) | ((unsigned)f2bf(sc[kt][1]*rn)<<16);
    pk[kt*2+1] = (unsigned)f2bf(sc[kt][2]*rn) | ((unsigned)f2bf(sc[kt][3]*rn)<<16);
  }
  // PV: A-frag = own pk[4ks..4ks+3]; B = Vt slots (permutation matches)
  f32x4 o0 = zero4, o1 = zero4;
  #pragma unroll
  for (int ks=0;ks<4;++ks){
    union { unsigned int u[4]; v8s v; } pa;
    pa.u[0]=pk[4*ks]; pa.u[1]=pk[4*ks+1]; pa.u[2]=pk[4*ks+2]; pa.u[3]=pk[4*ks+3];
    v8s v0 = *(const v8s*)&Vt[(     lr)*136 + ks*32 + lk*8];
    v8s v1 = *(const v8s*)&Vt[(16 + lr)*136 + ks*32 + lk*8];
    o0 = mfma16(pa.v, v0, o0);
    o1 = mfma16(pa.v, v1, o1);
  }
  // epilogue: lane holds O[s = wvq*16+lk*4+rr][d = lr | 16+lr]; transpose via ob
  #pragma unroll
  for (int rr=0;rr<4;++rr){
    int s = wvq*16 + lk*4 + rr;
    ob[s*36 + lr     ] = o0[rr];
    ob[s*36 + 16 + lr] = o1[rr];
  }
  // per-wave readback (wave-private rows): lane j -> row wvq*16+(j>>2), chunk j&3
  {
    int row = wvq*16 + (lane>>2), jj = lane&3;
    f32x4 fa = *(const f32x4*)&ob[row*36 + jj*8];
    f32x4 fb = *(const f32x4*)&ob[row*36 + jj*8 + 4];
    int pos = VERT ? row*128 + fix : fix*128 + row;
    size_t ga = ((size_t)b*16384 + pos)*256 + (size_t)(((head*4+jj)^(pos&31))<<3);
    if (VERT){
      v8s prev = *(const v8s*)(Ah + ga);
      v8s outv;
      #pragma unroll
      for (int j=0;j<4;++j){
        outv[j]   = (short)f2bf(bf2f((unsigned short)prev[j])   + fa[j]);
        outv[4+j] = (short)f2bf(bf2f((unsigned short)prev[4+j]) + fb[j]);
      }
      *(v8s*)(Ah + ga) = outv;
    } else {
      v8s outv;
      #pragma unroll
      for (int j=0;j<4;++j){
        outv[j]   = (short)f2bf(fa[j]);
        outv[4+j] = (short)f2bf(fb[j]);
      }
      *(v8s*)(Ah + ga) = outv;
    }
  }
}

// ---- final2: Ah (pre-swizzled bf16) via global_load_lds, GEMM Wo, +bias +x ----
__global__ __launch_bounds__(512,1)
void final2_kernel(const float* __restrict__ x, const unsigned short* __restrict__ wsWo,
                   const float* __restrict__ bo, const unsigned short* __restrict__ Ah,
                   float* __restrict__ out)
{
  __shared__ __align__(16) char smem[82048];
  unsigned short* asl = (unsigned short*)smem;            // [128 pos][256 c] swz
  unsigned short* wol = (unsigned short*)(smem + 65536);  // [32 o][256 c] swz
  float* bol          = (float*)(smem + 81920);           // [32]

  const int tid = threadIdx.x;
  const int b = blockIdx.x >> 7, pt = blockIdx.x & 127;
  {
    const char* ab = (const char*)(Ah + ((size_t)b*16384 + (size_t)pt*128)*256);
    for (int i=0;i<8;++i)
      gload_lds16(ab + (i*512+tid)*16, (char*)asl + (i*512+tid)*16);
  }
  const int lane = tid & 63, wv = tid >> 6;
  const int lr = lane & 15, lk = lane >> 4;
  const f32x4 zero4 = {0.f,0.f,0.f,0.f};

  for (int oc = 0; oc < 8; ++oc){
    {
      const char* wb = (const char*)wsWo + oc*16384;
      for (int rIt=0;rIt<2;++rIt)
        gload_lds16(wb + (rIt*512+tid)*16, (char*)wol + (rIt*512+tid)*16);
    }
    if (tid < 32) bol[tid] = bo[oc*32 + tid];
    __syncthreads();

    f32x4 a0 = zero4, a1 = zero4;
    #pragma unroll
    for (int ks = 0; ks < 8; ++ks){
      int c0 = ks*32 + lk*8;
      v8s av = *(const v8s*)(asl + xs_idx(wv*16 + lr, c0));
      v8s b0 = *(const v8s*)(wol + wl_idx(     lr, c0));
      v8s b1 = *(const v8s*)(wol + wl_idx(16 + lr, c0));
      a0 = mfma16(av, b0, a0);
      a1 = mfma16(av, b1, a1);
    }
    {
      int base0 = ((b*C_ + oc*32 + lr)*HH)*WW + pt*128 + wv*16 + lk*4;
      f32x4 xv0 = *(const f32x4*)(x + base0);
      f32x4 xv1 = *(const f32x4*)(x + base0 + 16*HH*WW);
      f32x4 r0 = a0 + xv0 + bol[lr];
      f32x4 r1 = a1 + xv1 + bol[16 + lr];
      *(f32x4*)(out + base0) = r0;
      *(f32x4*)(out + base0 + 16*HH*WW) = r1;
    }
    __syncthreads();
  }
}

// ============== fallback path (R3, proven; used if ws < WS_NEED2) ==============
template<int VERT>
__global__ __launch_bounds__(512,4)
void attn_kernel(const unsigned short* __restrict__ Qw, const unsigned short* __restrict__ Kw,
                 const unsigned short* __restrict__ Vw, float* __restrict__ osum){
  __shared__ __align__(16) char smem[53760];
  unsigned short* kl = (unsigned short*)smem;
  unsigned short* Vt = (unsigned short*)(smem + 10240);
  unsigned short* Pl = (unsigned short*)(smem + 18944);

  const int tid = threadIdx.x;
  int b, head, fix;
  if (VERT){ int xcd = blockIdx.x&7, rest = blockIdx.x>>3;
             fix = xcd*16 + (rest&15); head = (rest>>4)&7; b = rest>>7; }
  else     { head = blockIdx.x&7; fix = (blockIdx.x>>3)&127; b = blockIdx.x>>10; }
  const size_t tb = (size_t)(b*HEADS_+head)*16384*32;
  const int lane = tid&63, wv = tid>>6, lr = lane&15, lk = lane>>4;

  {
    int pl = tid>>2, ch = tid&3;
    size_t g = tb + ( VERT ? ((size_t)pl*128 + fix) : ((size_t)fix*128 + pl) )*32 + ch*8;
    v8s kv = *(const v8s*)(Kw + g);
    v8s vv = *(const v8s*)(Vw + g);
    *(v8s*)&kl[pl*40 + ch*8] = kv;
    #pragma unroll
    for (int j=0;j<8;++j) Vt[(ch*8+j)*136 + pl] = (unsigned short)vv[j];
  }
  const int posq = VERT ? (wv*16+lr)*128 + fix : fix*128 + wv*16+lr;
  v8s qa = *(const v8s*)(Qw + tb + (size_t)posq*32 + lk*8);
  __syncthreads();

  const f32x4 zero4 = {0.f,0.f,0.f,0.f};
  f32x4 sc[8];
  #pragma unroll
  for (int kt=0;kt<8;++kt){
    v8s kb = *(const v8s*)&kl[(kt*16+lr)*40 + lk*8];
    sc[kt] = mfma16(qa, kb, zero4);
  }
  float rn[4];
  #pragma unroll
  for (int rr=0;rr<4;++rr){
    float mx = sc[0][rr];
    #pragma unroll
    for (int kt=1;kt<8;++kt) mx = fmaxf(mx, sc[kt][rr]);
    #pragma unroll
    for (int off=1;off<16;off<<=1) mx = fmaxf(mx, __shfl_xor(mx, off, 16));
    float sm = 0.f;
    const int prow = (wv*16 + lk*4 + rr)*136;
    #pragma unroll
    for (int kt=0;kt<8;++kt){
      float p = __expf(sc[kt][rr]-mx);
      sm += p;
      Pl[prow + kt*16 + lr] = f2bf(p);
    }
    #pragma unroll
    for (int off=1;off<16;off<<=1) sm += __shfl_xor(sm, off, 16);
    rn[rr] = 1.f/sm;
  }
  f32x4 o0 = zero4, o1 = zero4;
  #pragma unroll
  for (int ks=0;ks<4;++ks){
    v8s pa = *(const v8s*)&Pl[(wv*16+lr)*136 + ks*32 + lk*8];
    v8s v0 = *(const v8s*)&Vt[(     lr)*136 + ks*32 + lk*8];
    v8s v1 = *(const v8s*)&Vt[(16 + lr)*136 + ks*32 + lk*8];
    o0 = mfma16(pa, v0, o0);
    o1 = mfma16(pa, v1, o1);
  }
  f32x4 rnv = {rn[0],rn[1],rn[2],rn[3]};
  o0 *= rnv; o1 *= rnv;
  if (!VERT){
    size_t base = ((size_t)(b*C_ + head*32 + lr)*HH + fix)*WW + wv*16 + lk*4;
    *(f32x4*)(osum + base) = o0;
    *(f32x4*)(osum + base + (size_t)16*HH*WW) = o1;
  } else {
    #pragma unroll
    for (int rr=0;rr<4;++rr){
      size_t g = ((size_t)(b*C_ + head*32 + lr)*HH + wv*16+lk*4+rr)*WW + fix;
      osum[g] += o0[rr];
      osum[g + (size_t)16*HH*WW] += o1[rr];
    }
  }
}

__global__ __launch_bounds__(512,1)
void final_fast_kernel(const float* __restrict__ x, const unsigned short* __restrict__ wsWo,
                       const float* __restrict__ bo, float* __restrict__ out)
{
  __shared__ __align__(16) char smem[82048];
  unsigned short* asl = (unsigned short*)smem;
  unsigned short* wol = (unsigned short*)(smem + 65536);
  float* bol          = (float*)(smem + 81920);

  const int tid = threadIdx.x;
  const int b = blockIdx.x >> 7, r = blockIdx.x & 127;
  {
    const int w = tid & 127, part = tid >> 7;
    #pragma unroll 4
    for (int it = 0; it < 32; ++it){
      int c = (it*4 + part)*2;
      int g0 = ((b*C_ + c)*HH + r)*WW + w;
      float f0 = out[g0], f1 = out[g0 + HH*WW];
      unsigned int pkv = (unsigned int)f2bf(f0) | ((unsigned int)f2bf(f1)<<16);
      *(unsigned int*)(asl + xs_idx(w,c)) = pkv;
    }
  }
  const int lane = tid & 63, wv = tid >> 6;
  const int lr = lane & 15, lk = lane >> 4;
  const f32x4 zero4 = {0.f,0.f,0.f,0.f};

  for (int oc = 0; oc < 8; ++oc){
    {
      const char* wb = (const char*)wsWo + oc*16384;
      for (int rIt=0;rIt<2;++rIt)
        gload_lds16(wb + (rIt*512+tid)*16, (char*)wol + (rIt*512+tid)*16);
    }
    if (tid < 32) bol[tid] = bo[oc*32 + tid];
    __syncthreads();

    f32x4 a0 = zero4, a1 = zero4;
    #pragma unroll
    for (int ks = 0; ks < 8; ++ks){
      int c0 = ks*32 + lk*8;
      v8s av = *(const v8s*)(asl + xs_idx(wv*16 + lr, c0));
      v8s b0 = *(const v8s*)(wol + wl_idx(     lr, c0));
      v8s b1 = *(const v8s*)(wol + wl_idx(16 + lr, c0));
      a0 = mfma16(av, b0, a0);
      a1 = mfma16(av, b1, a1);
    }
    {
      int base0 = ((b*C_ + oc*32 + lr)*HH + r)*WW + wv*16 + lk*4;
      f32x4 xv0 = *(const f32x4*)(x + base0);
      f32x4 xv1 = *(const f32x4*)(x + base0 + 16*HH*WW);
      f32x4 r0 = a0 + xv0 + bol[lr];
      f32x4 r1 = a1 + xv1 + bol[16 + lr];
      *(f32x4*)(out + base0) = r0;
      *(f32x4*)(out + base0 + 16*HH*WW) = r1;
    }
    __syncthreads();
  }
}

extern "C" void kernel_launch(void* const* d_in, const int* in_sizes, int n_in,
                              void* d_out, int out_size, void* d_ws, size_t ws_size,
                              hipStream_t stream) {
  const float* x  = (const float*)d_in[0];
  const float* Wq = (const float*)d_in[1];
  const float* bq = (const float*)d_in[2];
  const float* Wk = (const float*)d_in[3];
  const float* bk = (const float*)d_in[4];
  const float* Wv = (const float*)d_in[5];
  const float* bv = (const float*)d_in[6];
  const float* Wo = (const float*)d_in[7];
  const float* bo = (const float*)d_in[8];
  float* out = (float*)d_out;

  unsigned short* wsW  = (unsigned short*)d_ws;
  unsigned short* wsWo = (unsigned short*)((char*)d_ws + 393216);
  unsigned short* Qw   = (unsigned short*)((char*)d_ws + 524288);
  unsigned short* Kw   = Qw + 33554432;
  unsigned short* Vw   = Kw + 33554432;
  unsigned short* Ah   = (unsigned short*)((char*)d_ws + WS_NEED1);

  prep_w_kernel<<<dim3(128),  dim3(512), 0, stream>>>(Wq, Wk, Wv, Wo, wsW, wsWo);
  proj_kernel  <<<dim3(1024), dim3(512), 0, stream>>>(x, bq, bk, bv, wsW, Qw, Kw, Vw);
  if (ws_size >= WS_NEED2) {
    attn2_kernel<0><<<dim3(8192), dim3(512), 0, stream>>>(Qw, Kw, Vw, Ah);
    attn2_kernel<1><<<dim3(8192), dim3(512), 0, stream>>>(Qw, Kw, Vw, Ah);
    final2_kernel<<<dim3(1024), dim3(512), 0, stream>>>(x, wsWo, bo, Ah, out);
  } else {
    attn_kernel<0><<<dim3(8192), dim3(512), 0, stream>>>(Qw, Kw, Vw, out);
    attn_kernel<1><<<dim3(8192), dim3(512), 0, stream>>>(Qw, Kw, Vw, out);
    final_fast_kernel<<<dim3(1024), dim3(512), 0, stream>>>(x, wsWo, bo, out);
  }
}